// Round 1
// baseline (1014.378 us; speedup 1.0000x reference)
//
#include <hip/hip_runtime.h>

// EmbedLoopyBP on gfx950.
// Restructure: curW_t = cur_t @ Wc;  naW_t = segsum(curW_t, dst)
//   cur_{t+1} = relu(naW_t[src] - curW_t[rev] + bc + im);  curW_{t+1} = cur_{t+1} @ Wc
// Big [E,64] arrays stored bf16 (threshold = 2% of absmax -> safe), accumulation fp32.
// Segment sums via CSR gather (built per call); edge matmuls via mfma_f32_16x16x32_bf16.

#define NN 50000
#define NE 800000
#define NG 128
#define D 64

typedef unsigned short u16;
typedef unsigned int u32;
typedef __bf16 bf16x8 __attribute__((ext_vector_type(8)));
typedef float f32x4 __attribute__((ext_vector_type(4)));

__device__ __forceinline__ float b2f(u16 u){ u32 x=((u32)u)<<16; float f; __builtin_memcpy(&f,&x,4); return f; }
__device__ __forceinline__ u16 f2b(float f){ u32 x; __builtin_memcpy(&x,&f,4); x += 0x7fffu + ((x>>16)&1u); return (u16)(x>>16); }
__device__ __forceinline__ u32 pack2(float a, float b){ return (u32)f2b(a) | ((u32)f2b(b)<<16); }
__device__ __forceinline__ void unpack8(uint4 v, float* o){
  o[0]=b2f((u16)(v.x&0xffffu)); o[1]=b2f((u16)(v.x>>16));
  o[2]=b2f((u16)(v.y&0xffffu)); o[3]=b2f((u16)(v.y>>16));
  o[4]=b2f((u16)(v.z&0xffffu)); o[5]=b2f((u16)(v.z>>16));
  o[6]=b2f((u16)(v.w&0xffffu)); o[7]=b2f((u16)(v.w>>16));
}

// ---------------- node linear: inl = node_feat @ Wn + bn ----------------
__global__ __launch_bounds__(256) void k_inl(const float* __restrict__ nf, const float* __restrict__ Wn,
                                             const float* __restrict__ bn, float* __restrict__ inl){
  __shared__ float w[D*D];
  for (int i=threadIdx.x;i<D*D;i+=256) w[i]=Wn[i];
  __syncthreads();
  const int d = threadIdx.x&63;
  const int n = blockIdx.x*4 + (threadIdx.x>>6);
  if (n>=NN) return;
  float v = bn[d];
  const float* row = nf + (size_t)n*D;
  #pragma unroll 8
  for (int k=0;k<D;k++) v += row[k]*w[k*D+d];
  inl[(size_t)n*D+d] = v;
}

// ---------------- im = edge_feat @ We + be + inl[src]  (bf16 out) ----------------
#define LDE 40
__global__ __launch_bounds__(256) void k_im(const float* __restrict__ ef, const float* __restrict__ We,
                                            const float* __restrict__ be, const float* __restrict__ inl,
                                            const int* __restrict__ src, u16* __restrict__ im){
  __shared__ __align__(16) u16 efs[64*LDE];
  __shared__ __align__(16) u16 wts[64*LDE];
  __shared__ float os[64*D];
  const int t = threadIdx.x;
  const int ebase = blockIdx.x*64;
  { // stage We^T bf16 : wts[n][k], k<32
    int n=t&63, k0=(t>>6)*8;
    #pragma unroll
    for (int j=0;j<8;j++) wts[n*LDE + k0 + j] = f2b(We[(k0+j)*D + n]);
  }
  { // stage edge_feat bf16
    int e=t>>2, k0=(t&3)*8;
    const float* p = ef + (size_t)(ebase+e)*32 + k0;
    float4 v0=*(const float4*)p, v1=*(const float4*)(p+4);
    uint4 pk = make_uint4(pack2(v0.x,v0.y),pack2(v0.z,v0.w),pack2(v1.x,v1.y),pack2(v1.z,v1.w));
    *(uint4*)&efs[e*LDE + k0] = pk;
  }
  __syncthreads();
  { // MFMA 16x16x32 (K=32 exactly one step)
    int w=t>>6, lane=t&63, q=lane>>4, mr=lane&15;
    int rowb=w*16;
    bf16x8 A = *(const bf16x8*)&efs[(rowb+mr)*LDE + q*8];
    #pragma unroll
    for (int nt=0;nt<4;nt++){
      bf16x8 B = *(const bf16x8*)&wts[(nt*16+mr)*LDE + q*8];
      f32x4 acc = {0.f,0.f,0.f,0.f};
      acc = __builtin_amdgcn_mfma_f32_16x16x32_bf16(A,B,acc,0,0,0);
      #pragma unroll
      for (int r=0;r<4;r++) os[(rowb+q*4+r)*D + nt*16+mr] = acc[r];
    }
  }
  __syncthreads();
  { // epilogue: + be + inl[src[e]] -> bf16 im
    int e=t>>2, d0=(t&3)*16;
    const size_t eg = (size_t)(ebase+e);
    int s = src[eg];
    const float* ip = inl + (size_t)s*D + d0;
    const float* bp = be + d0;
    float x[16];
    #pragma unroll
    for (int j=0;j<16;j++) x[j] = os[e*D + d0 + j] + bp[j] + ip[j];
    uint4 p0 = make_uint4(pack2(x[0],x[1]),pack2(x[2],x[3]),pack2(x[4],x[5]),pack2(x[6],x[7]));
    uint4 p1 = make_uint4(pack2(x[8],x[9]),pack2(x[10],x[11]),pack2(x[12],x[13]),pack2(x[14],x[15]));
    u16* op = im + eg*D + d0;
    *(uint4*)op = p0; *(uint4*)(op+8) = p1;
  }
}

// ---------------- iteration kernel ----------------
// MODE 0: x=relu(im);                      out = (x@Wc) bf16
// MODE 1: x=relu(naW[src]-cin[rev]+bc+im); out = (x@Wc) bf16
// MODE 2: x=relu(naW[src]-cin[rev]+bc+im); out = x bf16 (no matmul; final cur_3)
#define LDX 72
template<int MODE>
__global__ __launch_bounds__(256) void k_iter(const u16* __restrict__ im, const u16* __restrict__ cin,
      const float* __restrict__ naW, const float* __restrict__ Wc, const float* __restrict__ bc,
      const int* __restrict__ src, const int* __restrict__ rev, u16* __restrict__ outb){
  __shared__ __align__(16) u16 xs[64*LDX];
  __shared__ __align__(16) u16 wts[64*LDX];
  __shared__ __align__(16) u16 os[4][16*D];
  const int t = threadIdx.x;
  const int ebase = blockIdx.x*64;
  if (MODE != 2){ // stage Wc^T bf16 : wts[n][k]
    int n=t&63, k0=(t>>6)*16;
    #pragma unroll
    for (int j=0;j<16;j++) wts[n*LDX + k0 + j] = f2b(Wc[(k0+j)*D + n]);
  }
  { // phase 1: elementwise, 4 threads per edge row
    const int e = t>>2, d0 = (t&3)*16;
    const size_t eg = (size_t)(ebase + e);
    const u16* imp = im + eg*D + d0;
    uint4 r0 = *(const uint4*)imp;
    uint4 r1 = *(const uint4*)(imp+8);
    float x[16];
    unpack8(r0, x); unpack8(r1, x+8);
    if (MODE != 0){
      const int s  = src[eg];
      const int rv = rev[eg];
      const u16* cp = cin + (size_t)rv*D + d0;
      uint4 c0 = *(const uint4*)cp;
      uint4 c1 = *(const uint4*)(cp+8);
      float cv[16]; unpack8(c0,cv); unpack8(c1,cv+8);
      const float* np_ = naW + (size_t)s*D + d0;
      float4 a0=*(const float4*)np_,     a1=*(const float4*)(np_+4);
      float4 a2=*(const float4*)(np_+8), a3=*(const float4*)(np_+12);
      float na[16] = {a0.x,a0.y,a0.z,a0.w, a1.x,a1.y,a1.z,a1.w,
                      a2.x,a2.y,a2.z,a2.w, a3.x,a3.y,a3.z,a3.w};
      float4 b0=*(const float4*)(bc+d0),   b1=*(const float4*)(bc+d0+4);
      float4 b2=*(const float4*)(bc+d0+8), b3=*(const float4*)(bc+d0+12);
      float bb[16] = {b0.x,b0.y,b0.z,b0.w, b1.x,b1.y,b1.z,b1.w,
                      b2.x,b2.y,b2.z,b2.w, b3.x,b3.y,b3.z,b3.w};
      #pragma unroll
      for (int j=0;j<16;j++) x[j] = na[j] - cv[j] + bb[j] + x[j];
    }
    #pragma unroll
    for (int j=0;j<16;j++) x[j] = x[j]>0.f ? x[j] : 0.f;
    uint4 p0 = make_uint4(pack2(x[0],x[1]),pack2(x[2],x[3]),pack2(x[4],x[5]),pack2(x[6],x[7]));
    uint4 p1 = make_uint4(pack2(x[8],x[9]),pack2(x[10],x[11]),pack2(x[12],x[13]),pack2(x[14],x[15]));
    if (MODE == 2){
      u16* op = outb + eg*D + d0;
      *(uint4*)op = p0; *(uint4*)(op+8) = p1;
    } else {
      u16* q = &xs[e*LDX + d0];
      *(uint4*)q = p0; *(uint4*)(q+8) = p1;
    }
  }
  if (MODE == 2) return;
  __syncthreads();
  { // phase 2: x @ Wc via MFMA, K=64 = 2 ksteps; wave w owns rows w*16..w*16+15
    const int w=t>>6, lane=t&63, q=lane>>4, mr=lane&15;
    const int rowb = w*16;
    bf16x8 A0 = *(const bf16x8*)&xs[(rowb+mr)*LDX + q*8];
    bf16x8 A1 = *(const bf16x8*)&xs[(rowb+mr)*LDX + 32 + q*8];
    #pragma unroll
    for (int nt=0;nt<4;nt++){
      bf16x8 B0 = *(const bf16x8*)&wts[(nt*16+mr)*LDX + q*8];
      bf16x8 B1 = *(const bf16x8*)&wts[(nt*16+mr)*LDX + 32 + q*8];
      f32x4 acc = {0.f,0.f,0.f,0.f};
      acc = __builtin_amdgcn_mfma_f32_16x16x32_bf16(A0,B0,acc,0,0,0);
      acc = __builtin_amdgcn_mfma_f32_16x16x32_bf16(A1,B1,acc,0,0,0);
      #pragma unroll
      for (int r=0;r<4;r++) os[w][(q*4+r)*D + nt*16 + mr] = f2b(acc[r]);
    }
    const int lr = lane>>2, c = lane&3;
    u16* gp = outb + (size_t)(ebase + rowb + lr)*D + c*16;
    *(uint4*)gp     = *(const uint4*)&os[w][lr*D + c*16];
    *(uint4*)(gp+8) = *(const uint4*)&os[w][lr*D + c*16 + 8];
  }
}

// ---------------- CSR-gather segment sum: out[n] = sum_{e: dst[e]==n} cur[e] ----------------
__global__ __launch_bounds__(256) void k_seg(const u16* __restrict__ cur, const int* __restrict__ off,
                                             const int* __restrict__ eid, float* __restrict__ outv){
  const int n = blockIdx.x*4 + (threadIdx.x>>6);
  const int lane = threadIdx.x&63;
  if (n>=NN) return;
  const int p0=off[n], p1=off[n+1];
  float acc=0.f;
  for (int p=p0;p<p1;p++){
    int e = eid[p];
    acc += b2f(cur[(size_t)e*D + lane]);
  }
  outv[(size_t)n*D+lane]=acc;
}

// ---------------- CSR build ----------------
__global__ void k_hist(const int* __restrict__ dst, int* __restrict__ cnt){
  int e = blockIdx.x*256 + threadIdx.x;
  atomicAdd(&cnt[dst[e]], 1);
}
__global__ __launch_bounds__(1024) void k_scan1(const int* __restrict__ cnt, int* __restrict__ outv,
                                                int* __restrict__ bsums, int n){
  __shared__ int sh[1024];
  int i = blockIdx.x*1024 + threadIdx.x;
  int v = (i<n)? cnt[i] : 0;
  sh[threadIdx.x]=v;
  __syncthreads();
  for (int off=1; off<1024; off<<=1){
    int tv = (threadIdx.x>=(unsigned)off)? sh[threadIdx.x-off] : 0;
    __syncthreads();
    sh[threadIdx.x] += tv;
    __syncthreads();
  }
  if (i<n) outv[i] = sh[threadIdx.x] - v;   // exclusive within block
  if (threadIdx.x==1023) bsums[blockIdx.x] = sh[1023];
}
__global__ void k_scan2(int* bsums, int nb, int* tot){
  if (threadIdx.x==0 && blockIdx.x==0){
    int run=0;
    for (int b=0;b<nb;b++){ int v=bsums[b]; bsums[b]=run; run+=v; }
    *tot = run;
  }
}
__global__ __launch_bounds__(1024) void k_scan3(int* __restrict__ off, int* __restrict__ cur,
                                                const int* __restrict__ bsums, int n){
  int i = blockIdx.x*1024 + threadIdx.x;
  if (i<n){ int v = off[i] + bsums[blockIdx.x]; off[i]=v; cur[i]=v; }
}
__global__ void k_fill(const int* __restrict__ dst, int* __restrict__ cur, int* __restrict__ eid){
  int e = blockIdx.x*256 + threadIdx.x;
  int pos = atomicAdd(&cur[dst[e]], 1);
  eid[pos] = e;
}

// ---------------- final: relu(e2n) @ Wo + bo -> relu -> segsum by graph ----------------
__global__ __launch_bounds__(256) void k_final(const float* __restrict__ e2n, const float* __restrict__ Wo,
                                               const float* __restrict__ bo, const int* __restrict__ gid,
                                               float* __restrict__ yacc){
  __shared__ float w[D*D];
  for (int i=threadIdx.x;i<D*D;i+=256) w[i]=Wo[i];
  __syncthreads();
  const int d = threadIdx.x&63, sub = threadIdx.x>>6;
  const int n0 = blockIdx.x*32 + sub*8;
  const float bod = bo[d];
  float acc=0.f; int curg=-1;
  for (int i=0;i<8;i++){
    int n=n0+i;
    if (n>=NN) break;
    int g = gid[n];
    if (g!=curg){ if (curg>=0) atomicAdd(&yacc[curg*D+d], acc); curg=g; acc=0.f; }
    float v=bod;
    const float* er = e2n + (size_t)n*D;
    #pragma unroll 8
    for (int k=0;k<D;k++){ float h=er[k]; h = h>0.f?h:0.f; v += h*w[k*D+d]; }
    acc += (v>0.f ? v : 0.f);
  }
  if (curg>=0) atomicAdd(&yacc[curg*D+d], acc);
}
__global__ void k_out(const float* __restrict__ yacc, float* __restrict__ outp){
  int i = blockIdx.x*256 + threadIdx.x;
  if (i<NG*D){ float v=yacc[i]; outp[i]= v>0.f?v:0.f; }
}

// ---------------- workspace layout ----------------
static constexpr size_t SZ_E   = (size_t)NE*D*2;        // 102,400,000 bf16 edge array
static constexpr size_t SZ_NF  = (size_t)NN*D*4;        // 12,800,000 f32 node array
static constexpr size_t OFF_IM   = 0;
static constexpr size_t OFF_CURA = SZ_E;
static constexpr size_t OFF_CURB = 2*SZ_E;
static constexpr size_t OFF_NAW  = 3*SZ_E;
static constexpr size_t OFF_INL  = OFF_NAW + SZ_NF;
static constexpr size_t OFF_E2N  = OFF_INL + SZ_NF;
static constexpr size_t OFF_COFF = OFF_E2N + SZ_NF;
static constexpr size_t OFF_CCUR = OFF_COFF + 200064;
static constexpr size_t OFF_CEID = OFF_CCUR + 200064;
static constexpr size_t OFF_BS   = OFF_CEID + (size_t)NE*4;
static constexpr size_t OFF_YACC = OFF_BS + 256;

extern "C" void kernel_launch(void* const* d_in, const int* in_sizes, int n_in,
                              void* d_out, int out_size, void* d_ws, size_t ws_size,
                              hipStream_t stream) {
  const float* node_feat = (const float*)d_in[0];
  const float* edge_feat = (const float*)d_in[1];
  const int*   src       = (const int*)d_in[2];
  const int*   dst       = (const int*)d_in[3];
  const int*   rev       = (const int*)d_in[4];
  const int*   gid       = (const int*)d_in[5];
  const float* Wn = (const float*)d_in[7];
  const float* bn = (const float*)d_in[8];
  const float* We = (const float*)d_in[9];
  const float* be = (const float*)d_in[10];
  const float* Wc = (const float*)d_in[11];
  const float* bc = (const float*)d_in[12];
  const float* Wo = (const float*)d_in[13];
  const float* bo = (const float*)d_in[14];

  char* ws = (char*)d_ws;
  u16*   im      = (u16*)(ws + OFF_IM);
  u16*   curA    = (u16*)(ws + OFF_CURA);
  u16*   curB    = (u16*)(ws + OFF_CURB);
  float* naW     = (float*)(ws + OFF_NAW);
  float* inl     = (float*)(ws + OFF_INL);
  float* e2n     = (float*)(ws + OFF_E2N);
  int*   csr_off = (int*)(ws + OFF_COFF);
  int*   csr_cur = (int*)(ws + OFF_CCUR);
  int*   csr_eid = (int*)(ws + OFF_CEID);
  int*   bsums   = (int*)(ws + OFF_BS);
  float* yacc    = (float*)(ws + OFF_YACC);

  hipMemsetAsync(csr_cur, 0, NN*sizeof(int), stream);
  hipMemsetAsync(yacc, 0, NG*D*sizeof(float), stream);

  // CSR build (by dst)
  k_hist <<<NE/256, 256, 0, stream>>>(dst, csr_cur);
  k_scan1<<<49, 1024, 0, stream>>>(csr_cur, csr_off, bsums, NN);
  k_scan2<<<1, 64, 0, stream>>>(bsums, 49, csr_off + NN);
  k_scan3<<<49, 1024, 0, stream>>>(csr_off, csr_cur, bsums, NN);
  k_fill <<<NE/256, 256, 0, stream>>>(dst, csr_cur, csr_eid);

  // front end
  k_inl<<<NN/4, 256, 0, stream>>>(node_feat, Wn, bn, inl);
  k_im <<<NE/64, 256, 0, stream>>>(edge_feat, We, be, inl, src, im);

  // curW_0 = relu(im) @ Wc
  k_iter<0><<<NE/64, 256, 0, stream>>>(im, curA, naW, Wc, bc, src, rev, curA);
  // iter 1
  k_seg<<<NN/4, 256, 0, stream>>>(curA, csr_off, csr_eid, naW);
  k_iter<1><<<NE/64, 256, 0, stream>>>(im, curA, naW, Wc, bc, src, rev, curB);
  // iter 2
  k_seg<<<NN/4, 256, 0, stream>>>(curB, csr_off, csr_eid, naW);
  k_iter<1><<<NE/64, 256, 0, stream>>>(im, curB, naW, Wc, bc, src, rev, curA);
  // iter 3 (final, no matmul -> cur_3)
  k_seg<<<NN/4, 256, 0, stream>>>(curA, csr_off, csr_eid, naW);
  k_iter<2><<<NE/64, 256, 0, stream>>>(im, curA, naW, Wc, bc, src, rev, curB);

  // e2n pool + final head
  k_seg<<<NN/4, 256, 0, stream>>>(curB, csr_off, csr_eid, e2n);
  k_final<<<(NN+31)/32, 256, 0, stream>>>(e2n, Wo, bo, gid, yacc);
  k_out<<<(NG*D)/256, 256, 0, stream>>>(yacc, (float*)d_out);
}

// Round 2
// 775.055 us; speedup vs baseline: 1.3088x; 1.3088x over previous
//
#include <hip/hip_runtime.h>

// EmbedLoopyBP on gfx950 — round 2.
// Key change vs round 1: edge state curW is stored in CSR(dst)-permuted order
// (curP[perm[e]] = row e). Segment-sum k_seg becomes a pure streaming reduction
// over contiguous segments (was a latency-bound eid-gather at 8% HBM, 100us x5).
// The rev-edge read in k_iter becomes a gather curP[perm[rev[e]]] — hidden by
// the kernel's streaming work + MFMA. perm[rev[e]] itself is a coalesced read.

#define NN 50000
#define NE 800000
#define NG 128
#define D 64

typedef unsigned short u16;
typedef unsigned int u32;
typedef __bf16 bf16x8 __attribute__((ext_vector_type(8)));
typedef float f32x4 __attribute__((ext_vector_type(4)));

__device__ __forceinline__ float b2f(u16 u){ u32 x=((u32)u)<<16; float f; __builtin_memcpy(&f,&x,4); return f; }
__device__ __forceinline__ u16 f2b(float f){ u32 x; __builtin_memcpy(&x,&f,4); x += 0x7fffu + ((x>>16)&1u); return (u16)(x>>16); }
__device__ __forceinline__ u32 pack2(float a, float b){ return (u32)f2b(a) | ((u32)f2b(b)<<16); }
__device__ __forceinline__ void unpack8(uint4 v, float* o){
  o[0]=b2f((u16)(v.x&0xffffu)); o[1]=b2f((u16)(v.x>>16));
  o[2]=b2f((u16)(v.y&0xffffu)); o[3]=b2f((u16)(v.y>>16));
  o[4]=b2f((u16)(v.z&0xffffu)); o[5]=b2f((u16)(v.z>>16));
  o[6]=b2f((u16)(v.w&0xffffu)); o[7]=b2f((u16)(v.w>>16));
}

// ---------------- node linear: inl = node_feat @ Wn + bn ----------------
__global__ __launch_bounds__(256) void k_inl(const float* __restrict__ nf, const float* __restrict__ Wn,
                                             const float* __restrict__ bn, float* __restrict__ inl){
  __shared__ float w[D*D];
  for (int i=threadIdx.x;i<D*D;i+=256) w[i]=Wn[i];
  __syncthreads();
  const int d = threadIdx.x&63;
  const int n = blockIdx.x*4 + (threadIdx.x>>6);
  if (n>=NN) return;
  float v = bn[d];
  const float* row = nf + (size_t)n*D;
  #pragma unroll 8
  for (int k=0;k<D;k++) v += row[k]*w[k*D+d];
  inl[(size_t)n*D+d] = v;
}

// ---------------- im = edge_feat @ We + be + inl[src]  (bf16 out, linear order) ----------------
#define LDE 40
__global__ __launch_bounds__(256) void k_im(const float* __restrict__ ef, const float* __restrict__ We,
                                            const float* __restrict__ be, const float* __restrict__ inl,
                                            const int* __restrict__ src, u16* __restrict__ im){
  __shared__ __align__(16) u16 efs[64*LDE];
  __shared__ __align__(16) u16 wts[64*LDE];
  __shared__ float os[64*D];
  const int t = threadIdx.x;
  const int ebase = blockIdx.x*64;
  { // stage We^T bf16 : wts[n][k], k<32
    int n=t&63, k0=(t>>6)*8;
    #pragma unroll
    for (int j=0;j<8;j++) wts[n*LDE + k0 + j] = f2b(We[(k0+j)*D + n]);
  }
  { // stage edge_feat bf16
    int e=t>>2, k0=(t&3)*8;
    const float* p = ef + (size_t)(ebase+e)*32 + k0;
    float4 v0=*(const float4*)p, v1=*(const float4*)(p+4);
    uint4 pk = make_uint4(pack2(v0.x,v0.y),pack2(v0.z,v0.w),pack2(v1.x,v1.y),pack2(v1.z,v1.w));
    *(uint4*)&efs[e*LDE + k0] = pk;
  }
  __syncthreads();
  { // MFMA 16x16x32 (K=32, one step)
    int w=t>>6, lane=t&63, q=lane>>4, mr=lane&15;
    int rowb=w*16;
    bf16x8 A = *(const bf16x8*)&efs[(rowb+mr)*LDE + q*8];
    #pragma unroll
    for (int nt=0;nt<4;nt++){
      bf16x8 B = *(const bf16x8*)&wts[(nt*16+mr)*LDE + q*8];
      f32x4 acc = {0.f,0.f,0.f,0.f};
      acc = __builtin_amdgcn_mfma_f32_16x16x32_bf16(A,B,acc,0,0,0);
      #pragma unroll
      for (int r=0;r<4;r++) os[(rowb+q*4+r)*D + nt*16+mr] = acc[r];
    }
  }
  __syncthreads();
  { // epilogue: + be + inl[src[e]] -> bf16 im (linear order)
    int e=t>>2, d0=(t&3)*16;
    const size_t eg = (size_t)(ebase+e);
    int s = src[eg];
    const float* ip = inl + (size_t)s*D + d0;
    const float* bp = be + d0;
    float x[16];
    #pragma unroll
    for (int j=0;j<16;j++) x[j] = os[e*D + d0 + j] + bp[j] + ip[j];
    uint4 p0 = make_uint4(pack2(x[0],x[1]),pack2(x[2],x[3]),pack2(x[4],x[5]),pack2(x[6],x[7]));
    uint4 p1 = make_uint4(pack2(x[8],x[9]),pack2(x[10],x[11]),pack2(x[12],x[13]),pack2(x[14],x[15]));
    u16* op = im + eg*D + d0;
    *(uint4*)op = p0; *(uint4*)(op+8) = p1;
  }
}

// ---------------- iteration kernel ----------------
// MODE 0: x=relu(im);                                   outP[perm[e]] = (x@Wc) bf16
// MODE 1: x=relu(naW[src]-cinP[perm[rev[e]]]+bc+im);    outP[perm[e]] = (x@Wc) bf16
// MODE 2: x=relu(naW[src]-cinP[perm[rev[e]]]+bc+im);    outP[perm[e]] = x bf16
#define LDX 72
template<int MODE>
__global__ __launch_bounds__(256) void k_iter(const u16* __restrict__ im, const u16* __restrict__ cinP,
      const float* __restrict__ naW, const float* __restrict__ Wc, const float* __restrict__ bc,
      const int* __restrict__ src, const int* __restrict__ rev, const int* __restrict__ perm,
      u16* __restrict__ outP){
  __shared__ __align__(16) u16 xs[64*LDX];
  __shared__ __align__(16) u16 wts[64*LDX];
  __shared__ __align__(16) u16 os[4][16*D];
  const int t = threadIdx.x;
  const int ebase = blockIdx.x*64;
  if (MODE != 2){ // stage Wc^T bf16 : wts[n][k]
    int n=t&63, k0=(t>>6)*16;
    #pragma unroll
    for (int j=0;j<16;j++) wts[n*LDX + k0 + j] = f2b(Wc[(k0+j)*D + n]);
  }
  { // phase 1: elementwise, 4 threads per edge row
    const int e = t>>2, d0 = (t&3)*16;
    const size_t eg = (size_t)(ebase + e);
    const u16* imp = im + eg*D + d0;
    uint4 r0 = *(const uint4*)imp;
    uint4 r1 = *(const uint4*)(imp+8);
    float x[16];
    unpack8(r0, x); unpack8(r1, x+8);
    if (MODE != 0){
      const int s  = src[eg];
      const int prv = perm[rev[eg]];          // coalesced: rev[e]=e+-400K
      const u16* cp = cinP + (size_t)prv*D + d0;   // gather of aligned 128B row
      uint4 c0 = *(const uint4*)cp;
      uint4 c1 = *(const uint4*)(cp+8);
      float cv[16]; unpack8(c0,cv); unpack8(c1,cv+8);
      const float* np_ = naW + (size_t)s*D + d0;
      float4 a0=*(const float4*)np_,     a1=*(const float4*)(np_+4);
      float4 a2=*(const float4*)(np_+8), a3=*(const float4*)(np_+12);
      float na[16] = {a0.x,a0.y,a0.z,a0.w, a1.x,a1.y,a1.z,a1.w,
                      a2.x,a2.y,a2.z,a2.w, a3.x,a3.y,a3.z,a3.w};
      float4 b0=*(const float4*)(bc+d0),   b1=*(const float4*)(bc+d0+4);
      float4 b2=*(const float4*)(bc+d0+8), b3=*(const float4*)(bc+d0+12);
      float bb[16] = {b0.x,b0.y,b0.z,b0.w, b1.x,b1.y,b1.z,b1.w,
                      b2.x,b2.y,b2.z,b2.w, b3.x,b3.y,b3.z,b3.w};
      #pragma unroll
      for (int j=0;j<16;j++) x[j] = na[j] - cv[j] + bb[j] + x[j];
    }
    #pragma unroll
    for (int j=0;j<16;j++) x[j] = x[j]>0.f ? x[j] : 0.f;
    uint4 p0 = make_uint4(pack2(x[0],x[1]),pack2(x[2],x[3]),pack2(x[4],x[5]),pack2(x[6],x[7]));
    uint4 p1 = make_uint4(pack2(x[8],x[9]),pack2(x[10],x[11]),pack2(x[12],x[13]),pack2(x[14],x[15]));
    if (MODE == 2){
      const int pslot = perm[eg];
      u16* op = outP + (size_t)pslot*D + d0;
      *(uint4*)op = p0; *(uint4*)(op+8) = p1;
    } else {
      u16* q = &xs[e*LDX + d0];
      *(uint4*)q = p0; *(uint4*)(q+8) = p1;
    }
  }
  if (MODE == 2) return;
  __syncthreads();
  { // phase 2: x @ Wc via MFMA, K=64 = 2 ksteps; wave w owns rows w*16..w*16+15
    const int w=t>>6, lane=t&63, q=lane>>4, mr=lane&15;
    const int rowb = w*16;
    bf16x8 A0 = *(const bf16x8*)&xs[(rowb+mr)*LDX + q*8];
    bf16x8 A1 = *(const bf16x8*)&xs[(rowb+mr)*LDX + 32 + q*8];
    #pragma unroll
    for (int nt=0;nt<4;nt++){
      bf16x8 B0 = *(const bf16x8*)&wts[(nt*16+mr)*LDX + q*8];
      bf16x8 B1 = *(const bf16x8*)&wts[(nt*16+mr)*LDX + 32 + q*8];
      f32x4 acc = {0.f,0.f,0.f,0.f};
      acc = __builtin_amdgcn_mfma_f32_16x16x32_bf16(A0,B0,acc,0,0,0);
      acc = __builtin_amdgcn_mfma_f32_16x16x32_bf16(A1,B1,acc,0,0,0);
      #pragma unroll
      for (int r=0;r<4;r++) os[w][(q*4+r)*D + nt*16 + mr] = f2b(acc[r]);
    }
    const int lr = lane>>2, c = lane&3;
    const int grow = ebase + rowb + lr;
    const int pslot = perm[grow];             // scatter to CSR slot
    u16* gp = outP + (size_t)pslot*D + c*16;
    *(uint4*)gp     = *(const uint4*)&os[w][lr*D + c*16];
    *(uint4*)(gp+8) = *(const uint4*)&os[w][lr*D + c*16 + 8];
  }
}

// ---------------- streaming segment sum over CSR-permuted rows ----------------
__global__ __launch_bounds__(256) void k_seg(const u16* __restrict__ curP, const int* __restrict__ off,
                                             float* __restrict__ outv){
  const int n = blockIdx.x*4 + (threadIdx.x>>6);
  const int lane = threadIdx.x&63;
  if (n>=NN) return;
  const int p0=off[n], p1=off[n+1];
  float a0=0.f,a1=0.f,a2=0.f,a3=0.f;
  int p=p0;
  for (; p+4<=p1; p+=4){
    a0 += b2f(curP[(size_t)(p+0)*D + lane]);
    a1 += b2f(curP[(size_t)(p+1)*D + lane]);
    a2 += b2f(curP[(size_t)(p+2)*D + lane]);
    a3 += b2f(curP[(size_t)(p+3)*D + lane]);
  }
  for (; p<p1; p++) a0 += b2f(curP[(size_t)p*D + lane]);
  outv[(size_t)n*D+lane] = (a0+a1)+(a2+a3);
}

// ---------------- CSR build (offsets + edge->slot permutation) ----------------
__global__ void k_hist(const int* __restrict__ dst, int* __restrict__ cnt){
  int e = blockIdx.x*256 + threadIdx.x;
  atomicAdd(&cnt[dst[e]], 1);
}
__global__ __launch_bounds__(1024) void k_scan1(const int* __restrict__ cnt, int* __restrict__ outv,
                                                int* __restrict__ bsums, int n){
  __shared__ int sh[1024];
  int i = blockIdx.x*1024 + threadIdx.x;
  int v = (i<n)? cnt[i] : 0;
  sh[threadIdx.x]=v;
  __syncthreads();
  for (int off=1; off<1024; off<<=1){
    int tv = (threadIdx.x>=(unsigned)off)? sh[threadIdx.x-off] : 0;
    __syncthreads();
    sh[threadIdx.x] += tv;
    __syncthreads();
  }
  if (i<n) outv[i] = sh[threadIdx.x] - v;   // exclusive within block
  if (threadIdx.x==1023) bsums[blockIdx.x] = sh[1023];
}
__global__ void k_scan2(int* bsums, int nb, int* tot){
  if (threadIdx.x==0 && blockIdx.x==0){
    int run=0;
    for (int b=0;b<nb;b++){ int v=bsums[b]; bsums[b]=run; run+=v; }
    *tot = run;
  }
}
__global__ __launch_bounds__(1024) void k_scan3(int* __restrict__ off, int* __restrict__ cur,
                                                const int* __restrict__ bsums, int n){
  int i = blockIdx.x*1024 + threadIdx.x;
  if (i<n){ int v = off[i] + bsums[blockIdx.x]; off[i]=v; cur[i]=v; }
}
__global__ void k_fill(const int* __restrict__ dst, int* __restrict__ cur, int* __restrict__ perm){
  int e = blockIdx.x*256 + threadIdx.x;
  int pos = atomicAdd(&cur[dst[e]], 1);
  perm[e] = pos;
}

// ---------------- final: relu(e2n) @ Wo + bo -> relu -> segsum by graph ----------------
__global__ __launch_bounds__(256) void k_final(const float* __restrict__ e2n, const float* __restrict__ Wo,
                                               const float* __restrict__ bo, const int* __restrict__ gid,
                                               float* __restrict__ yacc){
  __shared__ float w[D*D];
  for (int i=threadIdx.x;i<D*D;i+=256) w[i]=Wo[i];
  __syncthreads();
  const int d = threadIdx.x&63, sub = threadIdx.x>>6;
  const int n0 = blockIdx.x*32 + sub*8;
  const float bod = bo[d];
  float acc=0.f; int curg=-1;
  for (int i=0;i<8;i++){
    int n=n0+i;
    if (n>=NN) break;
    int g = gid[n];
    if (g!=curg){ if (curg>=0) atomicAdd(&yacc[curg*D+d], acc); curg=g; acc=0.f; }
    float v=bod;
    const float* er = e2n + (size_t)n*D;
    #pragma unroll 8
    for (int k=0;k<D;k++){ float h=er[k]; h = h>0.f?h:0.f; v += h*w[k*D+d]; }
    acc += (v>0.f ? v : 0.f);
  }
  if (curg>=0) atomicAdd(&yacc[curg*D+d], acc);
}
__global__ void k_out(const float* __restrict__ yacc, float* __restrict__ outp){
  int i = blockIdx.x*256 + threadIdx.x;
  if (i<NG*D){ float v=yacc[i]; outp[i]= v>0.f?v:0.f; }
}

// ---------------- workspace layout ----------------
static constexpr size_t SZ_E   = (size_t)NE*D*2;        // 102,400,000 bf16 edge array
static constexpr size_t SZ_NF  = (size_t)NN*D*4;        // 12,800,000 f32 node array
static constexpr size_t OFF_IM   = 0;
static constexpr size_t OFF_CPA  = SZ_E;
static constexpr size_t OFF_CPB  = 2*SZ_E;
static constexpr size_t OFF_NAW  = 3*SZ_E;
static constexpr size_t OFF_INL  = OFF_NAW + SZ_NF;
static constexpr size_t OFF_E2N  = OFF_INL + SZ_NF;
static constexpr size_t OFF_COFF = OFF_E2N + SZ_NF;
static constexpr size_t OFF_CCUR = OFF_COFF + 200064;
static constexpr size_t OFF_PERM = OFF_CCUR + 200064;
static constexpr size_t OFF_BS   = OFF_PERM + (size_t)NE*4;
static constexpr size_t OFF_YACC = OFF_BS + 256;

extern "C" void kernel_launch(void* const* d_in, const int* in_sizes, int n_in,
                              void* d_out, int out_size, void* d_ws, size_t ws_size,
                              hipStream_t stream) {
  const float* node_feat = (const float*)d_in[0];
  const float* edge_feat = (const float*)d_in[1];
  const int*   src       = (const int*)d_in[2];
  const int*   dst       = (const int*)d_in[3];
  const int*   rev       = (const int*)d_in[4];
  const int*   gid       = (const int*)d_in[5];
  const float* Wn = (const float*)d_in[7];
  const float* bn = (const float*)d_in[8];
  const float* We = (const float*)d_in[9];
  const float* be = (const float*)d_in[10];
  const float* Wc = (const float*)d_in[11];
  const float* bc = (const float*)d_in[12];
  const float* Wo = (const float*)d_in[13];
  const float* bo = (const float*)d_in[14];

  char* ws = (char*)d_ws;
  u16*   im      = (u16*)(ws + OFF_IM);
  u16*   curPA   = (u16*)(ws + OFF_CPA);
  u16*   curPB   = (u16*)(ws + OFF_CPB);
  float* naW     = (float*)(ws + OFF_NAW);
  float* inl     = (float*)(ws + OFF_INL);
  float* e2n     = (float*)(ws + OFF_E2N);
  int*   csr_off = (int*)(ws + OFF_COFF);
  int*   csr_cur = (int*)(ws + OFF_CCUR);
  int*   perm    = (int*)(ws + OFF_PERM);
  int*   bsums   = (int*)(ws + OFF_BS);
  float* yacc    = (float*)(ws + OFF_YACC);

  hipMemsetAsync(csr_cur, 0, NN*sizeof(int), stream);
  hipMemsetAsync(yacc, 0, NG*D*sizeof(float), stream);

  // CSR build (by dst): offsets + edge->slot perm
  k_hist <<<NE/256, 256, 0, stream>>>(dst, csr_cur);
  k_scan1<<<49, 1024, 0, stream>>>(csr_cur, csr_off, bsums, NN);
  k_scan2<<<1, 64, 0, stream>>>(bsums, 49, csr_off + NN);
  k_scan3<<<49, 1024, 0, stream>>>(csr_off, csr_cur, bsums, NN);
  k_fill <<<NE/256, 256, 0, stream>>>(dst, csr_cur, perm);

  // front end
  k_inl<<<NN/4, 256, 0, stream>>>(node_feat, Wn, bn, inl);
  k_im <<<NE/64, 256, 0, stream>>>(edge_feat, We, be, inl, src, im);

  // curW_0 = relu(im) @ Wc  -> permuted
  k_iter<0><<<NE/64, 256, 0, stream>>>(im, curPA, naW, Wc, bc, src, rev, perm, curPA);
  // iter 1
  k_seg<<<NN/4, 256, 0, stream>>>(curPA, csr_off, naW);
  k_iter<1><<<NE/64, 256, 0, stream>>>(im, curPA, naW, Wc, bc, src, rev, perm, curPB);
  // iter 2
  k_seg<<<NN/4, 256, 0, stream>>>(curPB, csr_off, naW);
  k_iter<1><<<NE/64, 256, 0, stream>>>(im, curPB, naW, Wc, bc, src, rev, perm, curPA);
  // iter 3 (final, no matmul -> cur_3 permuted)
  k_seg<<<NN/4, 256, 0, stream>>>(curPA, csr_off, naW);
  k_iter<2><<<NE/64, 256, 0, stream>>>(im, curPA, naW, Wc, bc, src, rev, perm, curPB);

  // e2n pool + final head
  k_seg<<<NN/4, 256, 0, stream>>>(curPB, csr_off, e2n);
  k_final<<<(NN+31)/32, 256, 0, stream>>>(e2n, Wo, bo, gid, yacc);
  k_out<<<(NG*D)/256, 256, 0, stream>>>(yacc, (float*)d_out);
}